// Round 1
// baseline (39800.763 us; speedup 1.0000x reference)
//
#include <hip/hip_runtime.h>
#include <math.h>

#define BB 64
#define TT 128
#define DBX 256
#define IND 264
#define HS 512
#define NH 4
#define MMM 128
#define AAA 2048
#define PPH 390
#define EPSF 1e-8f

__device__ __forceinline__ float sigmf(float x){ return 1.0f/(1.0f+expf(-x)); }
__device__ __forceinline__ float softplusf(float x){ return (x > 20.0f) ? x : log1pf(expf(x)); }

// ---------------- init ----------------
__global__ void k_init(float* __restrict__ h, float* __restrict__ rd,
                       float* __restrict__ wt, float* __restrict__ mem,
                       float* __restrict__ mn2){
  int i = blockIdx.x*blockDim.x + threadIdx.x;
  int stride = gridDim.x*blockDim.x;
  for (int idx=i; idx<BB*MMM*AAA; idx+=stride) mem[idx]=0.01f;
  for (int idx=i; idx<BB*HS; idx+=stride){ h[idx]=1.0f; rd[idx]=0.01f; }
  for (int idx=i; idx<BB*NH*AAA; idx+=stride) wt[idx] = ((idx & (AAA-1))==0)?1.0f:0.0f;
  for (int idx=i; idx<BB*AAA; idx+=stride) mn2[idx]=MMM*0.0001f; // 128 * 0.01^2
}

// ---------------- controller + out/upd GEMMs + param transforms ----------------
__global__ __launch_bounds__(1024) void k_ctrl(
    const float* __restrict__ x, const float* __restrict__ Wst, const float* __restrict__ bst,
    const float* __restrict__ Wout, const float* __restrict__ bout,
    const float* __restrict__ Wupd, const float* __restrict__ bupd,
    float* __restrict__ h, const float* __restrict__ readc, float* __restrict__ read_next,
    float* __restrict__ out,
    float* __restrict__ kvec, float* __restrict__ knorm, float* __restrict__ beta,
    float* __restrict__ gbuf, float* __restrict__ gam, float* __restrict__ shiftb,
    float* __restrict__ erase, float* __restrict__ addb,
    float* __restrict__ wcsum, float* __restrict__ wpsum, int t)
{
  __shared__ float cin[IND+HS+HS];   // 1288
  __shared__ float ph1[1024];
  __shared__ float hnew[HS];
  __shared__ float kl[NH*MMM];       // 512
  __shared__ float shr[NH*3];
  int b = blockIdx.x, tid = threadIdx.x;

  // stage ctrl_in = [x_t, h, read]
  for (int i=tid; i<IND; i+=1024) cin[i] = x[((size_t)b*TT + t)*IND + i];
  for (int i=tid; i<HS;  i+=1024) cin[IND+i]    = h[b*HS+i];
  for (int i=tid; i<HS;  i+=1024) cin[IND+HS+i] = readc[b*HS+i];
  // zero per-step accumulators
  if (tid < NH) wcsum[b*NH+tid] = 0.0f;
  else if (tid < 2*NH) wpsum[b*NH + tid-NH] = 0.0f;
  for (int i=tid; i<HS; i+=1024) read_next[b*HS+i] = 0.0f;
  __syncthreads();

  // phase 1: h_new = sigmoid(ctrl_in @ W_state + b_state), split-K by 2
  {
    int jj = tid & 511, half = tid >> 9;
    float acc = 0.0f;
    int k0 = half*644, k1 = k0+644; // 1288/2
    #pragma unroll 4
    for (int k=k0; k<k1; ++k) acc += cin[k]*Wst[(size_t)k*HS + jj];
    ph1[tid] = acc;
  }
  __syncthreads();
  if (tid < HS){
    float v = ph1[tid] + ph1[tid+512] + bst[tid];
    float hn = sigmf(v);
    hnew[tid] = hn;
    h[b*HS+tid] = hn;
  }
  __syncthreads();

  // phase 2: out (256 cols) + upd (1560 cols), K=512
  for (int c=tid; c<DBX+NH*PPH; c+=1024){
    const float* wcol; int strd; float acc;
    if (c < DBX){ wcol = Wout + c; strd = DBX; acc = bout[c]; }
    else        { int u = c-DBX; wcol = Wupd + u; strd = NH*PPH; acc = bupd[u]; }
    #pragma unroll 4
    for (int k=0; k<HS; ++k) acc += hnew[k]*wcol[(size_t)k*strd];
    if (c < DBX){
      out[((size_t)b*TT + t)*DBX + c] = sigmf(acc);
    } else {
      int u = c-DBX; int hh = u/PPH; int p = u - hh*PPH;
      if (p < MMM){ kvec[(b*NH+hh)*MMM + p] = acc; kl[hh*MMM+p] = acc; }
      else if (p == MMM)      beta[b*NH+hh] = softplusf(acc);
      else if (p == MMM+1)    gbuf[b*NH+hh] = sigmf(acc);
      else if (p <  MMM+5)    shr[hh*3 + (p-(MMM+2))] = acc;
      else if (p == MMM+5)    gam[b*NH+hh] = 1.0f + softplusf(acc);
      else if (p <  2*MMM+6)  erase[(b*NH+hh)*MMM + (p-(MMM+6))] = sigmf(acc);
      else                    addb[(b*NH+hh)*MMM + (p-(2*MMM+6))] = tanhf(acc);
    }
  }
  __syncthreads();

  // k_norm per (b,h)
  if (tid < 512) ph1[tid] = kl[tid]*kl[tid];
  __syncthreads();
  #pragma unroll
  for (int off=64; off>0; off>>=1){
    if (tid < 512 && (tid & 127) < off) ph1[tid] += ph1[tid+off];
    __syncthreads();
  }
  if (tid < NH) knorm[b*NH+tid] = sqrtf(ph1[tid*MMM]);
  // shift softmax (3-way)
  if (tid >= 64 && tid < 64+NH){
    int hh = tid-64;
    float s0=shr[hh*3], s1=shr[hh*3+1], s2=shr[hh*3+2];
    float mx = fmaxf(s0, fmaxf(s1, s2));
    float e0=expf(s0-mx), e1=expf(s1-mx), e2=expf(s2-mx);
    float inv = 1.0f/(e0+e1+e2);
    shiftb[(b*NH+hh)*3+0]=e0*inv;
    shiftb[(b*NH+hh)*3+1]=e1*inv;
    shiftb[(b*NH+hh)*3+2]=e2*inv;
  }
}

// ---------------- content dots + exp(beta*sim) ----------------
__global__ __launch_bounds__(512) void k_dots(
    const float* __restrict__ mem, const float* __restrict__ kvec,
    const float* __restrict__ knorm, const float* __restrict__ beta,
    const float* __restrict__ mn2, float* __restrict__ ebuf, float* __restrict__ wcsum)
{
  int b = blockIdx.x, s = blockIdx.y, tid = threadIdx.x;
  int a = s*512 + tid;
  __shared__ float kl[NH*MMM];
  __shared__ float rsum[8*NH];
  kl[tid] = kvec[b*NH*MMM + tid];
  __syncthreads();
  float a0=0,a1=0,a2=0,a3=0;
  const float* mp = mem + (size_t)b*MMM*AAA + a;
  #pragma unroll 4
  for (int m=0; m<MMM; ++m){
    float mv = mp[(size_t)m*AAA];
    a0 += kl[m]*mv; a1 += kl[MMM+m]*mv; a2 += kl[2*MMM+m]*mv; a3 += kl[3*MMM+m]*mv;
  }
  float mn = sqrtf(mn2[b*AAA + a]);
  float acc[4] = {a0,a1,a2,a3};
  int wid = tid >> 6, lane = tid & 63;
  #pragma unroll
  for (int hh=0; hh<NH; ++hh){
    float kn = knorm[b*NH+hh];
    float sim = acc[hh]/(kn*mn + EPSF);
    float e = expf(beta[b*NH+hh]*sim);
    ebuf[((size_t)(b*NH+hh))*AAA + a] = e;
    float v = e;
    #pragma unroll
    for (int off=32; off>0; off>>=1) v += __shfl_xor(v, off);
    if (lane==0) rsum[wid*NH+hh] = v;
  }
  __syncthreads();
  if (tid < NH){
    float s2 = 0.0f;
    #pragma unroll
    for (int w=0; w<8; ++w) s2 += rsum[w*NH+tid];
    atomicAdd(&wcsum[b*NH+tid], s2);
  }
}

// ---------------- normalize + interpolate + shift + sharpen ----------------
__global__ __launch_bounds__(512) void k_shift(
    const float* __restrict__ ebuf, const float* __restrict__ wcsum,
    const float* __restrict__ gbuf, const float* __restrict__ shiftb,
    const float* __restrict__ gam, const float* __restrict__ wt,
    float* __restrict__ wpb, float* __restrict__ wpsum)
{
  int b = blockIdx.x, s = blockIdx.y, tid = threadIdx.x;
  int a = s*512 + tid;
  int am1 = (a + AAA - 1) & (AAA-1);
  int ap1 = (a + 1) & (AAA-1);
  __shared__ float rsum[8*NH];
  int wid = tid >> 6, lane = tid & 63;
  #pragma unroll
  for (int hh=0; hh<NH; ++hh){
    const float* eb = ebuf + ((size_t)(b*NH+hh))*AAA;
    const float* wb = wt   + ((size_t)(b*NH+hh))*AAA;
    float inv = 1.0f/wcsum[b*NH+hh];
    float g   = gbuf[b*NH+hh];
    float s0 = shiftb[(b*NH+hh)*3+0];
    float s1 = shiftb[(b*NH+hh)*3+1];
    float s2 = shiftb[(b*NH+hh)*3+2];
    float gm = gam[b*NH+hh];
    float wgm1 = g*eb[am1]*inv + (1.0f-g)*wb[am1];
    float wg0  = g*eb[a]  *inv + (1.0f-g)*wb[a];
    float wgp1 = g*eb[ap1]*inv + (1.0f-g)*wb[ap1];
    float ws = s0*wgp1 + s1*wg0 + s2*wgm1;
    float wp = powf(ws + EPSF, gm);
    wpb[((size_t)(b*NH+hh))*AAA + a] = wp;
    float v = wp;
    #pragma unroll
    for (int off=32; off>0; off>>=1) v += __shfl_xor(v, off);
    if (lane==0) rsum[wid*NH+hh] = v;
  }
  __syncthreads();
  if (tid < NH){
    float s3 = 0.0f;
    #pragma unroll
    for (int w=0; w<8; ++w) s3 += rsum[w*NH+tid];
    atomicAdd(&wpsum[b*NH+tid], s3);
  }
}

// ---------------- wt_new + mem erase/add update + next read + next m_norm2 ----------------
__global__ __launch_bounds__(512) void k_upd(
    float* __restrict__ mem, const float* __restrict__ wpb, const float* __restrict__ wpsum,
    const float* __restrict__ erase, const float* __restrict__ addb,
    float* __restrict__ wt, float* __restrict__ read_next, float* __restrict__ mn2)
{
  int b = blockIdx.x, s = blockIdx.y, tid = threadIdx.x;
  int a = s*512 + tid;
  __shared__ float er[NH*MMM];
  __shared__ float ad[NH*MMM];
  __shared__ float rws[MMM*NH*8]; // [m][h][wave]
  er[tid] = erase[b*NH*MMM + tid];
  ad[tid] = addb[b*NH*MMM + tid];
  float wtn[NH];
  #pragma unroll
  for (int hh=0; hh<NH; ++hh){
    float w = wpb[((size_t)(b*NH+hh))*AAA + a] / wpsum[b*NH+hh];
    wtn[hh] = w;
    wt[((size_t)(b*NH+hh))*AAA + a] = w;
  }
  __syncthreads();
  int wid = tid >> 6, lane = tid & 63;
  float n2 = 0.0f;
  float* mp = mem + (size_t)b*MMM*AAA + a;
  for (int m=0; m<MMM; ++m){
    float mv = mp[(size_t)m*AAA];
    float et = (1.0f - er[m]*wtn[0]) * (1.0f - er[MMM+m]*wtn[1])
             * (1.0f - er[2*MMM+m]*wtn[2]) * (1.0f - er[3*MMM+m]*wtn[3]);
    float at = ad[m]*wtn[0] + ad[MMM+m]*wtn[1] + ad[2*MMM+m]*wtn[2] + ad[3*MMM+m]*wtn[3];
    float mnv = mv*et + at;
    mp[(size_t)m*AAA] = mnv;
    n2 += mnv*mnv;
    #pragma unroll
    for (int hh=0; hh<NH; ++hh){
      float r = mnv*wtn[hh];
      #pragma unroll
      for (int off=32; off>0; off>>=1) r += __shfl_xor(r, off);
      if (lane==0) rws[(m*NH+hh)*8 + wid] = r;
    }
  }
  mn2[b*AAA + a] = n2;
  __syncthreads();
  // i = m*4+h
  {
    int i = tid; // 0..511
    float v = 0.0f;
    #pragma unroll
    for (int w=0; w<8; ++w) v += rws[i*8 + w];
    int m = i >> 2, hh = i & 3;
    atomicAdd(&read_next[b*HS + hh*MMM + m], v);
  }
}

extern "C" void kernel_launch(void* const* d_in, const int* in_sizes, int n_in,
                              void* d_out, int out_size, void* d_ws, size_t ws_size,
                              hipStream_t stream){
  const float* x    = (const float*)d_in[0];
  const float* Wst  = (const float*)d_in[1];
  const float* bst  = (const float*)d_in[2];
  const float* Wout = (const float*)d_in[3];
  const float* bout = (const float*)d_in[4];
  const float* Wupd = (const float*)d_in[5];
  const float* bupd = (const float*)d_in[6];
  float* out = (float*)d_out;

  float* p = (float*)d_ws;
  float* h      = p; p += BB*HS;          // 32768
  float* rbuf   = p; p += 2*BB*HS;        // 65536 (ping-pong read)
  float* wt     = p; p += BB*NH*AAA;      // 524288
  float* mem    = p; p += (size_t)BB*MMM*AAA; // 16777216
  float* mn2    = p; p += BB*AAA;         // 131072
  float* kvec   = p; p += BB*NH*MMM;      // 32768
  float* knorm  = p; p += BB*NH;
  float* beta   = p; p += BB*NH;
  float* gbuf   = p; p += BB*NH;
  float* gam    = p; p += BB*NH;
  float* shiftb = p; p += BB*NH*3;
  float* erase  = p; p += BB*NH*MMM;
  float* addb   = p; p += BB*NH*MMM;
  float* ebuf   = p; p += BB*NH*AAA;      // 524288
  float* wpb    = p; p += BB*NH*AAA;      // 524288
  float* wcsum  = p; p += BB*NH;
  float* wpsum  = p; p += BB*NH;

  k_init<<<2048, 256, 0, stream>>>(h, rbuf, wt, mem, mn2);
  for (int t=0; t<TT; ++t){
    const float* rc = rbuf + (t&1)*BB*HS;
    float* rn = rbuf + ((t+1)&1)*BB*HS;
    k_ctrl<<<dim3(BB), 1024, 0, stream>>>(x, Wst, bst, Wout, bout, Wupd, bupd,
        h, rc, rn, out, kvec, knorm, beta, gbuf, gam, shiftb, erase, addb, wcsum, wpsum, t);
    k_dots<<<dim3(BB,4), 512, 0, stream>>>(mem, kvec, knorm, beta, mn2, ebuf, wcsum);
    k_shift<<<dim3(BB,4), 512, 0, stream>>>(ebuf, wcsum, gbuf, shiftb, gam, wt, wpb, wpsum);
    k_upd<<<dim3(BB,4), 512, 0, stream>>>(mem, wpb, wpsum, erase, addb, wt, rn, mn2);
  }
}

// Round 2
// 14726.807 us; speedup vs baseline: 2.7026x; 2.7026x over previous
//
#include <hip/hip_runtime.h>
#include <math.h>

#define BB 64
#define TT 128
#define DBX 256
#define IND 264
#define HS 512
#define NH 4
#define MMM 128
#define AAA 2048
#define PPH 390
#define NCOLS (DBX + NH*PPH)   // 2072
#define EPSF 1e-8f

__device__ __forceinline__ float sigmf(float x){ return 1.0f/(1.0f+expf(-x)); }
__device__ __forceinline__ float softplusf(float x){ return (x > 20.0f) ? x : log1pf(expf(x)); }

// ---------------- init ----------------
__global__ void k_init(float* __restrict__ h0, float* __restrict__ rd,
                       float* __restrict__ wt, float* __restrict__ mem){
  int i = blockIdx.x*blockDim.x + threadIdx.x;
  int stride = gridDim.x*blockDim.x;
  for (int idx=i; idx<BB*MMM*AAA; idx+=stride) mem[idx]=0.01f;
  for (int idx=i; idx<BB*HS; idx+=stride){ h0[idx]=1.0f; rd[idx]=0.01f; }
  for (int idx=i; idx<BB*NH*AAA; idx+=stride) wt[idx] = ((idx & (AAA-1))==0)?1.0f:0.0f;
}

// ---------------- phase 1: h_new = sigmoid([x,h,read] @ W_state + b) ----------------
__global__ __launch_bounds__(256) void k1_state(
    const float* __restrict__ x, const float* __restrict__ Wst, const float* __restrict__ bst,
    const float* __restrict__ hprev, const float* __restrict__ readc, float* __restrict__ hnew_g,
    float* __restrict__ wcsum, float* __restrict__ wpsum, int t)
{
  __shared__ __align__(16) float cin[1288];
  __shared__ float ph[256];
  int b = blockIdx.x, ch = blockIdx.y, tid = threadIdx.x;
  for (int i=tid;i<IND;i+=256) cin[i]       = x[((size_t)b*TT+t)*IND+i];
  for (int i=tid;i<HS; i+=256) cin[IND+i]   = hprev[b*HS+i];
  for (int i=tid;i<HS; i+=256) cin[IND+HS+i]= readc[b*HS+i];
  if (ch==0){
    if (tid<NH) wcsum[b*NH+tid]=0.0f;
    else if (tid<2*NH) wpsum[b*NH+tid-NH]=0.0f;
  }
  __syncthreads();
  int j = ch*128 + (tid&127);
  int half = tid>>7;                      // split-K by 2: 644 each (16B aligned)
  const float4* c4 = (const float4*)(cin + half*644);
  const float* wp = Wst + (size_t)(half*644)*HS + j;
  float acc = 0.0f;
  #pragma unroll 4
  for (int q=0; q<161; ++q){
    float4 cv = c4[q];
    const float* w = wp + (size_t)(q*4)*HS;
    acc += cv.x*w[0] + cv.y*w[HS] + cv.z*w[2*HS] + cv.w*w[3*HS];
  }
  ph[tid] = acc;
  __syncthreads();
  if (tid < 128){
    float v = ph[tid] + ph[tid+128] + bst[j];
    hnew_g[b*HS+j] = sigmf(v);
  }
}

// ---------------- phase 2: out + upd GEMV + param transforms ----------------
__global__ __launch_bounds__(256) void k2_outupd(
    const float* __restrict__ hnew_g,
    const float* __restrict__ Wout, const float* __restrict__ bout,
    const float* __restrict__ Wupd, const float* __restrict__ bupd,
    float* __restrict__ out,
    float* __restrict__ kvec_t, float* __restrict__ beta, float* __restrict__ gbuf,
    float* __restrict__ gam, float* __restrict__ shraw,
    float* __restrict__ erase, float* __restrict__ addb, int t)
{
  __shared__ __align__(16) float hn[HS];
  int b = blockIdx.x, ch = blockIdx.y, tid = threadIdx.x;
  for (int i=tid;i<HS;i+=256) hn[i] = hnew_g[b*HS+i];
  __syncthreads();
  int c = ch*256 + tid;
  if (c >= NCOLS) return;
  const float* wcol; size_t strd; float acc;
  if (c < DBX){ wcol = Wout + c; strd = DBX;    acc = bout[c]; }
  else        { int u = c-DBX; wcol = Wupd + u; strd = NH*PPH; acc = bupd[u]; }
  const float4* h4 = (const float4*)hn;
  #pragma unroll 4
  for (int q=0; q<128; ++q){
    float4 hv = h4[q];
    const float* w = wcol + (size_t)(4*q)*strd;
    acc += hv.x*w[0] + hv.y*w[strd] + hv.z*w[2*strd] + hv.w*w[3*strd];
  }
  if (c < DBX){
    out[((size_t)b*TT + t)*DBX + c] = sigmf(acc);
  } else {
    int u = c-DBX; int hh = u/PPH; int p = u - hh*PPH;
    if (p < MMM)            kvec_t[b*HS + p*NH + hh] = acc;        // [m][h] transposed
    else if (p == MMM)      beta[b*NH+hh] = softplusf(acc);
    else if (p == MMM+1)    gbuf[b*NH+hh] = sigmf(acc);
    else if (p <  MMM+5)    shraw[(b*NH+hh)*3 + (p-(MMM+2))] = acc;
    else if (p == MMM+5)    gam[b*NH+hh] = 1.0f + softplusf(acc);
    else if (p <  2*MMM+6)  erase[b*HS + hh*MMM + (p-(MMM+6))] = sigmf(acc);
    else                    addb[b*HS + hh*MMM + (p-(2*MMM+6))] = tanhf(acc);
  }
}

// ---------------- content dots + knorm + mnorm + exp(beta*sim) ----------------
__global__ __launch_bounds__(512) void k_dots(
    const float* __restrict__ mem, const float* __restrict__ kvec_t,
    const float* __restrict__ beta,
    float* __restrict__ ebuf, float* __restrict__ wcsum, float* __restrict__ readb)
{
  int b = blockIdx.x, s = blockIdx.y, tid = threadIdx.x;
  __shared__ __align__(16) float klt[HS];   // [m][h]
  __shared__ float red[HS];
  __shared__ float kn[NH];
  __shared__ float rsum[8*NH];
  klt[tid] = kvec_t[b*HS + tid];
  if (s == 0) readb[b*HS + tid] = 0.0f;     // zero read accumulator for this step
  __syncthreads();
  red[tid] = klt[tid]*klt[tid];
  __syncthreads();
  #pragma unroll
  for (int off=256; off>=4; off>>=1){
    if (tid < off) red[tid] += red[tid+off];
    __syncthreads();
  }
  if (tid < NH) kn[tid] = sqrtf(red[tid]);
  __syncthreads();

  int a = s*512 + tid;
  const float* mp = mem + (size_t)b*MMM*AAA + a;
  const float4* k4 = (const float4*)klt;
  float a0=0,a1=0,a2=0,a3=0,n2=0;
  #pragma unroll 4
  for (int m=0; m<MMM; ++m){
    float mv = mp[(size_t)m*AAA];
    float4 kv = k4[m];
    a0 += kv.x*mv; a1 += kv.y*mv; a2 += kv.z*mv; a3 += kv.w*mv;
    n2 += mv*mv;
  }
  float mn = sqrtf(n2);
  float acc[NH] = {a0,a1,a2,a3};
  int wid = tid >> 6, lane = tid & 63;
  #pragma unroll
  for (int hh=0; hh<NH; ++hh){
    float sim = acc[hh]/(kn[hh]*mn + EPSF);
    float e = expf(beta[b*NH+hh]*sim);
    ebuf[((size_t)(b*NH+hh))*AAA + a] = e;
    float v = e;
    #pragma unroll
    for (int off=32; off>0; off>>=1) v += __shfl_xor(v, off);
    if (lane==0) rsum[wid*NH+hh] = v;
  }
  __syncthreads();
  if (tid < NH){
    float s2 = 0.0f;
    #pragma unroll
    for (int w=0; w<8; ++w) s2 += rsum[w*NH+tid];
    atomicAdd(&wcsum[b*NH+tid], s2);
  }
}

// ---------------- normalize + interpolate + shift + sharpen ----------------
__global__ __launch_bounds__(512) void k_shift(
    const float* __restrict__ ebuf, const float* __restrict__ wcsum,
    const float* __restrict__ gbuf, const float* __restrict__ shraw,
    const float* __restrict__ gam, const float* __restrict__ wt,
    float* __restrict__ wpb, float* __restrict__ wpsum)
{
  int b = blockIdx.x, s = blockIdx.y, tid = threadIdx.x;
  int a = s*512 + tid;
  int am1 = (a + AAA - 1) & (AAA-1);
  int ap1 = (a + 1) & (AAA-1);
  __shared__ float sh[NH*3], gl[NH], gml[NH], winv[NH];
  __shared__ float rsum[8*NH];
  if (tid < NH){
    int hh = tid;
    float s0=shraw[(b*NH+hh)*3], s1=shraw[(b*NH+hh)*3+1], s2=shraw[(b*NH+hh)*3+2];
    float mx = fmaxf(s0, fmaxf(s1, s2));
    float e0=expf(s0-mx), e1=expf(s1-mx), e2=expf(s2-mx);
    float inv = 1.0f/(e0+e1+e2);
    sh[hh*3+0]=e0*inv; sh[hh*3+1]=e1*inv; sh[hh*3+2]=e2*inv;
    gl[hh]  = gbuf[b*NH+hh];
    gml[hh] = gam[b*NH+hh];
    winv[hh]= 1.0f/wcsum[b*NH+hh];
  }
  __syncthreads();
  int wid = tid >> 6, lane = tid & 63;
  #pragma unroll
  for (int hh=0; hh<NH; ++hh){
    const float* eb = ebuf + ((size_t)(b*NH+hh))*AAA;
    const float* wb = wt   + ((size_t)(b*NH+hh))*AAA;
    float inv = winv[hh], g = gl[hh];
    float s0 = sh[hh*3+0], s1 = sh[hh*3+1], s2 = sh[hh*3+2];
    float wgm1 = g*eb[am1]*inv + (1.0f-g)*wb[am1];
    float wg0  = g*eb[a]  *inv + (1.0f-g)*wb[a];
    float wgp1 = g*eb[ap1]*inv + (1.0f-g)*wb[ap1];
    float ws = s0*wgp1 + s1*wg0 + s2*wgm1;
    float wp = powf(ws + EPSF, gml[hh]);
    wpb[((size_t)(b*NH+hh))*AAA + a] = wp;
    float v = wp;
    #pragma unroll
    for (int off=32; off>0; off>>=1) v += __shfl_xor(v, off);
    if (lane==0) rsum[wid*NH+hh] = v;
  }
  __syncthreads();
  if (tid < NH){
    float s3 = 0.0f;
    #pragma unroll
    for (int w=0; w<8; ++w) s3 += rsum[w*NH+tid];
    atomicAdd(&wpsum[b*NH+tid], s3);
  }
}

// ---------------- wt_new + mem update (regs) + read einsum (transposed phase B) ----------------
__global__ __launch_bounds__(512) void k_upd(
    float* __restrict__ mem, const float* __restrict__ wpb, const float* __restrict__ wpsum,
    const float* __restrict__ erase, const float* __restrict__ addb,
    float* __restrict__ wt, float* __restrict__ readb)
{
  int b = blockIdx.x, s = blockIdx.y, tid = threadIdx.x;
  int a = s*512 + tid;
  __shared__ __align__(16) float ert[HS];      // [m][h]
  __shared__ __align__(16) float adt[HS];      // [m][h]
  __shared__ __align__(16) float wtl[512*NH];  // [col_in_chunk][h], 8KB
  {
    int m = tid & 127, hh = tid >> 7;
    ert[m*NH+hh] = erase[b*HS + hh*MMM + m];
    adt[m*NH+hh] = addb[b*HS + hh*MMM + m];
  }
  float wtn[NH];
  #pragma unroll
  for (int hh=0; hh<NH; ++hh){
    float w = wpb[((size_t)(b*NH+hh))*AAA + a] / wpsum[b*NH+hh];
    wtn[hh] = w;
    wt[((size_t)(b*NH+hh))*AAA + a] = w;
    wtl[tid*NH+hh] = w;
  }
  __syncthreads();

  float* mp = mem + (size_t)b*MMM*AAA + a;
  const float4* e4 = (const float4*)ert;
  const float4* a4 = (const float4*)adt;
  #pragma unroll 4
  for (int m=0; m<MMM; ++m){
    float mv = mp[(size_t)m*AAA];
    float4 ev = e4[m], av = a4[m];
    float et = (1.0f - ev.x*wtn[0]) * (1.0f - ev.y*wtn[1])
             * (1.0f - ev.z*wtn[2]) * (1.0f - ev.w*wtn[3]);
    float at = av.x*wtn[0] + av.y*wtn[1] + av.z*wtn[2] + av.w*wtn[3];
    mp[(size_t)m*AAA] = mv*et + at;
  }
  __syncthreads();

  // phase B: read[b,h,m] partial over this block's 512-column slice
  int m = tid >> 2, sl = tid & 3;
  const float* row = mem + (size_t)b*MMM*AAA + (size_t)m*AAA + s*512 + sl*128;
  const float4* w4 = (const float4*)wtl;
  float r0=0,r1=0,r2=0,r3=0;
  #pragma unroll 4
  for (int j=0; j<128; ++j){
    float mv = row[j];
    float4 wv = w4[sl*128 + j];
    r0 += mv*wv.x; r1 += mv*wv.y; r2 += mv*wv.z; r3 += mv*wv.w;
  }
  float racc[NH] = {r0,r1,r2,r3};
  #pragma unroll
  for (int hh=0; hh<NH; ++hh){
    float v = racc[hh];
    v += __shfl_xor(v, 1);
    v += __shfl_xor(v, 2);
    racc[hh] = v;
  }
  if (sl == 0){
    #pragma unroll
    for (int hh=0; hh<NH; ++hh)
      atomicAdd(&readb[b*HS + hh*MMM + m], racc[hh]);
  }
}

extern "C" void kernel_launch(void* const* d_in, const int* in_sizes, int n_in,
                              void* d_out, int out_size, void* d_ws, size_t ws_size,
                              hipStream_t stream){
  const float* x    = (const float*)d_in[0];
  const float* Wst  = (const float*)d_in[1];
  const float* bst  = (const float*)d_in[2];
  const float* Wout = (const float*)d_in[3];
  const float* bout = (const float*)d_in[4];
  const float* Wupd = (const float*)d_in[5];
  const float* bupd = (const float*)d_in[6];
  float* out = (float*)d_out;

  float* p = (float*)d_ws;
  float* hb     = p; p += 2*BB*HS;            // ping-pong h
  float* readb  = p; p += BB*HS;
  float* wt     = p; p += BB*NH*AAA;
  float* mem    = p; p += (size_t)BB*MMM*AAA;
  float* kvec_t = p; p += BB*HS;
  float* beta   = p; p += BB*NH;
  float* gbuf   = p; p += BB*NH;
  float* gam    = p; p += BB*NH;
  float* shraw  = p; p += BB*NH*3;
  float* erase  = p; p += BB*HS;
  float* addb   = p; p += BB*HS;
  float* ebuf   = p; p += BB*NH*AAA;
  float* wpb    = p; p += BB*NH*AAA;
  float* wcsum  = p; p += BB*NH;
  float* wpsum  = p; p += BB*NH;

  k_init<<<2048, 256, 0, stream>>>(hb, readb, wt, mem);
  for (int t=0; t<TT; ++t){
    const float* hp = hb + (t&1)*BB*HS;
    float* hn       = hb + ((t+1)&1)*BB*HS;
    k1_state<<<dim3(BB,4), 256, 0, stream>>>(x, Wst, bst, hp, readb, hn, wcsum, wpsum, t);
    k2_outupd<<<dim3(BB,9), 256, 0, stream>>>(hn, Wout, bout, Wupd, bupd, out,
        kvec_t, beta, gbuf, gam, shraw, erase, addb, t);
    k_dots<<<dim3(BB,4), 512, 0, stream>>>(mem, kvec_t, beta, ebuf, wcsum, readb);
    k_shift<<<dim3(BB,4), 512, 0, stream>>>(ebuf, wcsum, gbuf, shraw, gam, wt, wpb, wpsum);
    k_upd<<<dim3(BB,4), 512, 0, stream>>>(mem, wpb, wpsum, erase, addb, wt, readb);
  }
}